// Round 1
// 467.125 us; speedup vs baseline: 1.1773x; 1.1773x over previous
//
#include <hip/hip_runtime.h>

// ---------------------------------------------------------------------------
// MultiheadSelfAttentionRoPE  (f32 inputs -> **f32 output**)
//   B=2, S=2048, D=2048, H=16, dk=128, causal, RoPE interleaved pairs.
// Pipeline:
//   0) cast (grid.z=5): x, Wq, Wk, Wv, Wo  f32 -> bf16 workspace copies
//   1) gemm_bt<bf16> (grid.z=3): Q,K,V = x @ W{q,k,v}^T    [4096x2048] bf16
//   2) rope: in-place RoPE on Q and K (1 sincos per (s,pair), 4 sites)
//   3) vtrans: V -> Vt [b][h][128][2048] (Vt in low half of d_out scratch)
//   4) attn: flash MFMA attention -> Ab (aliases Vb; Vb dead after 3)
//      v2: KVBLK=64, T14 reg-prefetch staging, swapped-operand QK^T
//      (in-lane softmax reduce), LPT dispatch, setprio around MFMA.
//   5) gemm_bt<float> (grid.z=1): out = Ab @ Wo^T -> d_out (f32 stores)
// Workspace: xb 16.78 + 4*Wb 33.55 + Q/K/V 50.33 = 100.7 MB.
// ---------------------------------------------------------------------------

#define AS1 __attribute__((address_space(1)))
#define AS3 __attribute__((address_space(3)))

typedef __bf16 bf16;
typedef float f32x4 __attribute__((ext_vector_type(4)));
typedef bf16 bf16x8 __attribute__((ext_vector_type(8)));
typedef bf16 bf16x4 __attribute__((ext_vector_type(4)));
typedef bf16 bf16x2 __attribute__((ext_vector_type(2)));

#define SEQ 2048
#define DMODEL 2048
#define NH 16
#define DK 128

// ---------------------------------------------------------------------------
// Cast f32 -> bf16.  z=0: x (8.4M elems);  z=1..4: weights (4.19M each).
// ---------------------------------------------------------------------------
__global__ __launch_bounds__(256) void cast_f32_bf16(
    const float* __restrict__ s0, const float* __restrict__ s1,
    const float* __restrict__ s2, const float* __restrict__ s3,
    const float* __restrict__ s4,
    bf16* __restrict__ d0, bf16* __restrict__ d1, bf16* __restrict__ d2,
    bf16* __restrict__ d3, bf16* __restrict__ d4)
{
    const int z = blockIdx.z;
    const float* s = (z == 0) ? s0 : (z == 1) ? s1 : (z == 2) ? s2 : (z == 3) ? s3 : s4;
    bf16*        d = (z == 0) ? d0 : (z == 1) ? d1 : (z == 2) ? d2 : (z == 3) ? d3 : d4;
    const int n = (z == 0) ? (4096 * 2048) : (2048 * 2048);
    const int i = (blockIdx.x * 256 + threadIdx.x) * 4;
    if (i >= n) return;
    const f32x4 v = *(const f32x4*)(s + i);
    bf16x4 r;
    r[0] = (bf16)v[0]; r[1] = (bf16)v[1]; r[2] = (bf16)v[2]; r[3] = (bf16)v[3];
    *(bf16x4*)(d + i) = r;
}

// ---------------------------------------------------------------------------
// GEMM: C = A @ B^T.  A [M][K] bf16, B [N][K] bf16, C [M][N] of type CT.
// 128x128 block tile, BK=32, 4 waves in 2x2, each wave 4x4 16x16x32 MFMA.
// m97 structure: global_load_lds width=16 staging, unpadded [128][32] LDS.
// Verified layouts: A-frag  A[m=lane&15][k=quad*8+j]
//                   B-frag  B^T[n=lane&15][k=quad*8+j]
//                   C/D     row=quad*4+reg, col=lane&15
// ---------------------------------------------------------------------------
template <typename CT>
__global__ __launch_bounds__(256, 2) void gemm_bt(
    const bf16* __restrict__ A,
    const bf16* __restrict__ B0, const bf16* __restrict__ B1, const bf16* __restrict__ B2,
    CT* __restrict__ C0, CT* __restrict__ C1, CT* __restrict__ C2,
    int M, int N, int K)
{
    const bf16* B = (blockIdx.z == 0) ? B0 : ((blockIdx.z == 1) ? B1 : B2);
    CT* C = (blockIdx.z == 0) ? C0 : ((blockIdx.z == 1) ? C1 : C2);

    __shared__ __align__(16) bf16 sA[128 * 32];
    __shared__ __align__(16) bf16 sB[128 * 32];

    const int tid  = threadIdx.x;
    const int m0   = blockIdx.y * 128;
    const int n0   = blockIdx.x * 128;
    const int lane = tid & 63;
    const int wave = tid >> 6;
    const int wr   = (wave >> 1) * 64;
    const int wc   = (wave & 1) * 64;
    const int l16  = lane & 15;
    const int quad = lane >> 4;

    f32x4 acc[4][4] = {};

    const int rowS = tid >> 2;
    const int c8   = (tid & 3) * 8;
    const bf16* gA = A + (m0 + rowS) * K + c8;
    const bf16* gB = B + (n0 + rowS) * K + c8;
    AS3 bf16* lA = (AS3 bf16*)sA + tid * 8;
    AS3 bf16* lB = (AS3 bf16*)sB + tid * 8;

    for (int k0 = 0; k0 < K; k0 += 32) {
        __syncthreads();
        __builtin_amdgcn_global_load_lds((const AS1 void*)(gA + k0),          (AS3 void*)lA,          16, 0, 0);
        __builtin_amdgcn_global_load_lds((const AS1 void*)(gA + 64 * K + k0), (AS3 void*)(lA + 2048), 16, 0, 0);
        __builtin_amdgcn_global_load_lds((const AS1 void*)(gB + k0),          (AS3 void*)lB,          16, 0, 0);
        __builtin_amdgcn_global_load_lds((const AS1 void*)(gB + 64 * K + k0), (AS3 void*)(lB + 2048), 16, 0, 0);
        __syncthreads();

        bf16x8 a[4], b[4];
#pragma unroll
        for (int t = 0; t < 4; t++)
            a[t] = *(const bf16x8*)(sA + (wr + t * 16 + l16) * 32 + quad * 8);
#pragma unroll
        for (int t = 0; t < 4; t++)
            b[t] = *(const bf16x8*)(sB + (wc + t * 16 + l16) * 32 + quad * 8);
#pragma unroll
        for (int i = 0; i < 4; i++)
#pragma unroll
            for (int j = 0; j < 4; j++)
                acc[i][j] = __builtin_amdgcn_mfma_f32_16x16x32_bf16(a[i], b[j], acc[i][j], 0, 0, 0);
    }

#pragma unroll
    for (int i = 0; i < 4; i++) {
        const int r0 = m0 + wr + i * 16 + quad * 4;
#pragma unroll
        for (int j = 0; j < 4; j++) {
            const int c = n0 + wc + j * 16 + l16;
#pragma unroll
            for (int r = 0; r < 4; r++)
                C[(size_t)(r0 + r) * N + c] = (CT)acc[i][j][r];
        }
    }
}

// ---------------------------------------------------------------------------
// RoPE in-place on Q and K.  One thread per (s, pair); each thread applies
// its rotation to 4 sites (b=0,1 x Q,K) -> 4x fewer sincosf than v1.
// pair pr = h*64 + p; cols 2pr, 2pr+1; phase = s * 10000^(-p/64).
// ---------------------------------------------------------------------------
__global__ __launch_bounds__(256) void rope_kernel(bf16* __restrict__ Q,
                                                   bf16* __restrict__ K)
{
    const int idx = blockIdx.x * 256 + threadIdx.x;   // 2048*1024 threads
    const int pr  = idx & 1023;
    const int s   = idx >> 10;
    const int p   = pr & 63;

    // log2(10000)/64 = 0.20762050593046836
    const float ph = (float)s * exp2f(-(float)p * 0.20762050593046836f);
    float sn, cs;
    sincosf(ph, &sn, &cs);

#pragma unroll
    for (int t = 0; t < 2; t++) {
        bf16* P = t ? K : Q;
#pragma unroll
        for (int b = 0; b < 2; b++) {
            bf16* ptr = P + (size_t)(b * SEQ + s) * DMODEL + pr * 2;
            bf16x2 v = *(const bf16x2*)ptr;
            const float x1 = (float)v[0], x2 = (float)v[1];
            bf16x2 r;
            r[0] = (bf16)(x1 * cs - x2 * sn);
            r[1] = (bf16)(x1 * sn + x2 * cs);
            *(bf16x2*)ptr = r;
        }
    }
}

// ---------------------------------------------------------------------------
// V transpose: V [b*S+s][h*128+d] -> Vt [(b*16+h)*128+d][s]
// ---------------------------------------------------------------------------
__global__ __launch_bounds__(256) void vtrans(const bf16* __restrict__ V,
                                              bf16* __restrict__ Vt)
{
    __shared__ bf16 t[32][33];
    const int bh = blockIdx.z;
    const int s0 = blockIdx.x * 32;
    const int d0 = blockIdx.y * 32;
    const int b = bh >> 4, h = bh & 15;
    const int tx = threadIdx.x & 31, ty = threadIdx.x >> 5;

#pragma unroll
    for (int i = 0; i < 4; i++) {
        const int s = s0 + ty + i * 8;
        t[ty + i * 8][tx] = V[(size_t)(b * SEQ + s) * DMODEL + h * DK + d0 + tx];
    }
    __syncthreads();
#pragma unroll
    for (int i = 0; i < 4; i++) {
        const int d = d0 + ty + i * 8;
        Vt[(size_t)(bh * DK + d) * SEQ + s0 + tx] = t[tx][ty + i * 8];
    }
}

// ---------------------------------------------------------------------------
// Flash-style causal MFMA attention v2.
// Block = 4 waves; block owns (b, h, 64 q-rows); each wave owns 16 q-rows.
// KVBLK=64.  Swapped QK^T: sa = mfma(K-frag, Q-frag) ->
//   S[kv = kt*64 + sub*16 + quad*4 + r][q = q0 + l16]  (lane l16 = q-row)
// so the softmax row-reduce is in-lane over 16 regs + shfl_xor(16|32).
// P is written to sP[q][kv] and re-read in the verified A-frag layout
// (A[m=l16][k=quad*8+j]) for PV; o/epilogue layout unchanged from v1.
// T14: next tile's K/V global->reg loads are issued before compute so the
// HBM latency hides under the MFMA+softmax phase; ds_write happens after
// the next barrier.  LPT: qt reversed so heaviest blocks dispatch first.
// ---------------------------------------------------------------------------
#define NEG 3.0e4f

__global__ __launch_bounds__(256, 3) void attn(
    const bf16* __restrict__ Q, const bf16* __restrict__ K,
    const bf16* __restrict__ Vt, bf16* __restrict__ O)
{
    const int qt = (gridDim.x - 1) - blockIdx.x;   // LPT: heavy blocks first
    const int h = blockIdx.y, b = blockIdx.z;
    const int tid = threadIdx.x, lane = tid & 63, wave = tid >> 6;
    const int l16 = lane & 15, quad = lane >> 4;

    __shared__ __align__(16) bf16 sK[64 * 136];     // 17.4 KB, pad 8
    __shared__ __align__(16) bf16 sV[128 * 72];     // 18.4 KB, pad 8
    __shared__ __align__(16) bf16 sP[4][16 * 72];   //  9.2 KB, pad 8

    const int q0 = qt * 64 + wave * 16;

    bf16x8 qf[4];
    const bf16* gQ = Q + (size_t)(b * SEQ + q0 + l16) * DMODEL + h * DK + quad * 8;
#pragma unroll
    for (int dc = 0; dc < 4; dc++) qf[dc] = *(const bf16x8*)(gQ + dc * 32);

    f32x4 o[8] = {};
    float mrow = -NEG;      // stats for q-row (q0 + l16), replicated per quad
    float lrow = 0.f;

    const bf16* gK = K + (size_t)(b * SEQ) * DMODEL + h * DK;
    const bf16* gV = Vt + (size_t)((b * NH + h) * DK) * SEQ;

    const float scale = 0.12751744154470187f;  // (1/sqrt(128)) * log2(e)
    const int nkt = qt + 1;                    // 64-wide kv tiles

    // staging geometry: 4 x bf16x8 per thread per tensor
    const int rK = tid >> 4;           // K rows rK + 16*i   (0..63)
    const int cK = (tid & 15) * 8;     // K col chunk
    const int dV = tid >> 3;           // Vt rows dV + 32*i  (0..127)
    const int cV = (tid & 7) * 8;      // kv col chunk

    bf16x8 kreg[4], vreg[4];
    {   // prologue: load tile 0
#pragma unroll
        for (int i = 0; i < 4; i++)
            kreg[i] = *(const bf16x8*)(gK + (size_t)(rK + 16 * i) * DMODEL + cK);
#pragma unroll
        for (int i = 0; i < 4; i++)
            vreg[i] = *(const bf16x8*)(gV + (size_t)(dV + 32 * i) * SEQ + cV);
    }

    for (int kt = 0; kt < nkt; kt++) {
        __syncthreads();               // prev compute done with LDS
#pragma unroll
        for (int i = 0; i < 4; i++)
            *(bf16x8*)(sK + (rK + 16 * i) * 136 + cK) = kreg[i];
#pragma unroll
        for (int i = 0; i < 4; i++)
            *(bf16x8*)(sV + (dV + 32 * i) * 72 + cV) = vreg[i];
        __syncthreads();

        if (kt + 1 < nkt) {            // T14: issue next tile early
            const int kb0 = (kt + 1) * 64;
#pragma unroll
            for (int i = 0; i < 4; i++)
                kreg[i] = *(const bf16x8*)(gK + (size_t)(kb0 + rK + 16 * i) * DMODEL + cK);
#pragma unroll
            for (int i = 0; i < 4; i++)
                vreg[i] = *(const bf16x8*)(gV + (size_t)(dV + 32 * i) * SEQ + kb0 + cV);
        }

        if (kt * 64 <= q0 + 15) {      // wave-uniform causal skip
            // ---- QK^T, swapped operands: lane l16 = q-row ----
            f32x4 s4[4] = {};
            __builtin_amdgcn_s_setprio(1);
#pragma unroll
            for (int sub = 0; sub < 4; sub++)
#pragma unroll
                for (int dc = 0; dc < 4; dc++) {
                    bf16x8 kb = *(const bf16x8*)(sK + (sub * 16 + l16) * 136 + dc * 32 + quad * 8);
                    s4[sub] = __builtin_amdgcn_mfma_f32_16x16x32_bf16(kb, qf[dc], s4[sub], 0, 0, 0);
                }
            __builtin_amdgcn_s_setprio(0);

            // ---- mask + in-lane softmax over 16 kv values/lane ----
            const int qg = q0 + l16;
            const int kb0 = kt * 64 + quad * 4;
            float arr[16];
            float mx = -NEG;
#pragma unroll
            for (int sub = 0; sub < 4; sub++)
#pragma unroll
                for (int r = 0; r < 4; r++) {
                    const int key = kb0 + sub * 16 + r;
                    const float val = (key <= qg) ? s4[sub][r] * scale : -NEG;
                    arr[sub * 4 + r] = val;
                    mx = fmaxf(mx, val);
                }
            mx = fmaxf(mx, __shfl_xor(mx, 16));
            mx = fmaxf(mx, __shfl_xor(mx, 32));
            const float mnew  = fmaxf(mrow, mx);
            const float alpha = exp2f(mrow - mnew);
            mrow = mnew;
            float ps = 0.f;
#pragma unroll
            for (int i = 0; i < 16; i++) {
                arr[i] = exp2f(arr[i] - mnew);
                ps += arr[i];
            }
            ps += __shfl_xor(ps, 16);
            ps += __shfl_xor(ps, 32);
            lrow = lrow * alpha + ps;

            // ---- P -> sP (row q=l16, col kv) ----
#pragma unroll
            for (int sub = 0; sub < 4; sub++) {
                bf16x4 pk;
                pk[0] = (bf16)arr[sub * 4 + 0];
                pk[1] = (bf16)arr[sub * 4 + 1];
                pk[2] = (bf16)arr[sub * 4 + 2];
                pk[3] = (bf16)arr[sub * 4 + 3];
                *(bf16x4*)&sP[wave][l16 * 72 + sub * 16 + quad * 4] = pk;
            }

            // ---- rescale o: alpha for o-row (quad*4+r) via width-16 shfl ----
#pragma unroll
            for (int r = 0; r < 4; r++) {
                const float ar = __shfl(alpha, quad * 4 + r, 16);
#pragma unroll
                for (int dt = 0; dt < 8; dt++) o[dt][r] *= ar;
            }

            asm volatile("s_waitcnt lgkmcnt(0)" ::: "memory");
            __builtin_amdgcn_sched_barrier(0);

            // ---- PV: verified A-frag layout A[m=l16][k=quad*8+j] ----
            const bf16x8 pf0 = *(const bf16x8*)&sP[wave][l16 * 72 + quad * 8];
            const bf16x8 pf1 = *(const bf16x8*)&sP[wave][l16 * 72 + 32 + quad * 8];
            __builtin_amdgcn_s_setprio(1);
#pragma unroll
            for (int dt = 0; dt < 8; dt++) {
                bf16x8 vf0 = *(const bf16x8*)(sV + (dt * 16 + l16) * 72 + quad * 8);
                o[dt] = __builtin_amdgcn_mfma_f32_16x16x32_bf16(pf0, vf0, o[dt], 0, 0, 0);
                bf16x8 vf1 = *(const bf16x8*)(sV + (dt * 16 + l16) * 72 + 32 + quad * 8);
                o[dt] = __builtin_amdgcn_mfma_f32_16x16x32_bf16(pf1, vf1, o[dt], 0, 0, 0);
            }
            __builtin_amdgcn_s_setprio(0);
        }
    }

    // epilogue: l for o-row (quad*4+r) via width-16 shfl, then divide+store
    bf16* gO = O + (size_t)(b * SEQ + q0 + quad * 4) * DMODEL + h * DK + l16;
#pragma unroll
    for (int r = 0; r < 4; r++) {
        const float lr = __shfl(lrow, quad * 4 + r, 16);
        const float inv = 1.0f / lr;
#pragma unroll
        for (int dt = 0; dt < 8; dt++)
            gO[(size_t)r * DMODEL + dt * 16] = (bf16)(o[dt][r] * inv);
    }
}

// ---------------------------------------------------------------------------
extern "C" void kernel_launch(void* const* d_in, const int* in_sizes, int n_in,
                              void* d_out, int out_size, void* d_ws, size_t ws_size,
                              hipStream_t stream)
{
    const float* x  = (const float*)d_in[0];
    const float* Wq = (const float*)d_in[2];
    const float* Wk = (const float*)d_in[3];
    const float* Wv = (const float*)d_in[4];
    const float* Wo = (const float*)d_in[5];

    const int M = 2 * SEQ;       // 4096
    const int N = DMODEL;        // 2048
    const int Kd = DMODEL;       // 2048
    const size_t tsz = (size_t)M * N;   // 8.4M elems
    const size_t wsz = (size_t)N * Kd;  // 4.2M elems

    // Workspace layout (bf16): xb | Wqb Wkb Wvb Wob | Qb Kb Vb  = 100.7 MB
    bf16* xb  = (bf16*)d_ws;
    bf16* Wqb = xb  + tsz;
    bf16* Wkb = Wqb + wsz;
    bf16* Wvb = Wkb + wsz;
    bf16* Wob = Wvb + wsz;
    bf16* Qb  = Wob + wsz;
    bf16* Kb  = Qb  + tsz;
    bf16* Vb  = Kb  + tsz;
    bf16* Vt  = (bf16*)d_out;    // scratch in d_out (33.5 MB as f32); fully
                                 // overwritten by the final f32 GEMM stores
    bf16* Ab  = Vb;              // alias: Vb dead once Vt is built

    // 0) cast all f32 inputs to bf16
    cast_f32_bf16<<<dim3(tsz / 1024, 1, 5), 256, 0, stream>>>(
        x, Wq, Wk, Wv, Wo, xb, Wqb, Wkb, Wvb, Wob);

    // 1) Q,K,V projections (fused via grid.z), bf16 outputs
    gemm_bt<bf16><<<dim3(N / 128, M / 128, 3), 256, 0, stream>>>(
        xb, Wqb, Wkb, Wvb, Qb, Kb, Vb, M, N, Kd);

    // 2) RoPE on Q and K (1 sincos per (s,pair) -> 4 sites)
    rope_kernel<<<(SEQ * 1024) / 256, 256, 0, stream>>>(Qb, Kb);

    // 3) transpose V per (b,h) into d_out scratch
    vtrans<<<dim3(SEQ / 32, DK / 32, 2 * NH), 256, 0, stream>>>(Vb, Vt);

    // 4) causal flash attention -> Ab (Vb's storage)
    attn<<<dim3(SEQ / 64, NH, 2), 256, 0, stream>>>(Qb, Kb, Vt, Ab);

    // 5) output projection -> d_out, FLOAT32 stores (reference output dtype)
    gemm_bt<float><<<dim3(N / 128, M / 128, 1), 256, 0, stream>>>(
        Ab, Wob, Wob, Wob, (float*)d_out, (float*)d_out, (float*)d_out, M, N, Kd);
}

// Round 2
// 434.290 us; speedup vs baseline: 1.2663x; 1.0756x over previous
//
#include <hip/hip_runtime.h>

// ---------------------------------------------------------------------------
// MultiheadSelfAttentionRoPE  (f32 inputs -> **f32 output**)
//   B=2, S=2048, D=2048, H=16, dk=128, causal, RoPE interleaved pairs.
// Pipeline:
//   0) cast (grid.z=5): x, Wq, Wk, Wv, Wo  f32 -> bf16 workspace copies
//   1) gemm_bt<bf16> (grid.z=3): Q,K,V = x @ W{q,k,v}^T    [4096x2048] bf16
//   2) rope: in-place RoPE on Q and K (1 sincos per (s,pair), 4 sites)
//   3) vtrans: V -> Vt [b][h][128][2048] (Vt in low half of d_out scratch)
//   4) attn: flash MFMA attention -> Ab (aliases Vb; Vb dead after 3)
//      v3: BM=128 (wave owns 32 q-rows, kb/vf fragments reused 2x -> LDS
//      read traffic per FLOP halved), T2 XOR-swizzled sK/sV/sP (no pads),
//      KVBLK=64, T14 reg-prefetch staging, swapped-operand QK^T with
//      in-lane softmax, balanced-pair LPT dispatch, setprio around MFMA.
//   5) gemm_bt<float> (grid.z=1): out = Ab @ Wo^T -> d_out (f32 stores)
// Workspace: xb 16.78 + 4*Wb 33.55 + Q/K/V 50.33 = 100.7 MB.
// ---------------------------------------------------------------------------

#define AS1 __attribute__((address_space(1)))
#define AS3 __attribute__((address_space(3)))

typedef __bf16 bf16;
typedef float f32x4 __attribute__((ext_vector_type(4)));
typedef bf16 bf16x8 __attribute__((ext_vector_type(8)));
typedef bf16 bf16x4 __attribute__((ext_vector_type(4)));
typedef bf16 bf16x2 __attribute__((ext_vector_type(2)));

#define SEQ 2048
#define DMODEL 2048
#define NH 16
#define DK 128

// ---------------------------------------------------------------------------
// Cast f32 -> bf16.  z=0: x (8.4M elems);  z=1..4: weights (4.19M each).
// ---------------------------------------------------------------------------
__global__ __launch_bounds__(256) void cast_f32_bf16(
    const float* __restrict__ s0, const float* __restrict__ s1,
    const float* __restrict__ s2, const float* __restrict__ s3,
    const float* __restrict__ s4,
    bf16* __restrict__ d0, bf16* __restrict__ d1, bf16* __restrict__ d2,
    bf16* __restrict__ d3, bf16* __restrict__ d4)
{
    const int z = blockIdx.z;
    const float* s = (z == 0) ? s0 : (z == 1) ? s1 : (z == 2) ? s2 : (z == 3) ? s3 : s4;
    bf16*        d = (z == 0) ? d0 : (z == 1) ? d1 : (z == 2) ? d2 : (z == 3) ? d3 : d4;
    const int n = (z == 0) ? (4096 * 2048) : (2048 * 2048);
    const int i = (blockIdx.x * 256 + threadIdx.x) * 4;
    if (i >= n) return;
    const f32x4 v = *(const f32x4*)(s + i);
    bf16x4 r;
    r[0] = (bf16)v[0]; r[1] = (bf16)v[1]; r[2] = (bf16)v[2]; r[3] = (bf16)v[3];
    *(bf16x4*)(d + i) = r;
}

// ---------------------------------------------------------------------------
// GEMM: C = A @ B^T.  A [M][K] bf16, B [N][K] bf16, C [M][N] of type CT.
// 128x128 block tile, BK=32, 4 waves in 2x2, each wave 4x4 16x16x32 MFMA.
// m97 structure: global_load_lds width=16 staging, unpadded [128][32] LDS.
// Verified layouts: A-frag  A[m=lane&15][k=quad*8+j]
//                   B-frag  B^T[n=lane&15][k=quad*8+j]
//                   C/D     row=quad*4+reg, col=lane&15
// ---------------------------------------------------------------------------
template <typename CT>
__global__ __launch_bounds__(256, 2) void gemm_bt(
    const bf16* __restrict__ A,
    const bf16* __restrict__ B0, const bf16* __restrict__ B1, const bf16* __restrict__ B2,
    CT* __restrict__ C0, CT* __restrict__ C1, CT* __restrict__ C2,
    int M, int N, int K)
{
    const bf16* B = (blockIdx.z == 0) ? B0 : ((blockIdx.z == 1) ? B1 : B2);
    CT* C = (blockIdx.z == 0) ? C0 : ((blockIdx.z == 1) ? C1 : C2);

    __shared__ __align__(16) bf16 sA[128 * 32];
    __shared__ __align__(16) bf16 sB[128 * 32];

    const int tid  = threadIdx.x;
    const int m0   = blockIdx.y * 128;
    const int n0   = blockIdx.x * 128;
    const int lane = tid & 63;
    const int wave = tid >> 6;
    const int wr   = (wave >> 1) * 64;
    const int wc   = (wave & 1) * 64;
    const int l16  = lane & 15;
    const int quad = lane >> 4;

    f32x4 acc[4][4] = {};

    const int rowS = tid >> 2;
    const int c8   = (tid & 3) * 8;
    const bf16* gA = A + (m0 + rowS) * K + c8;
    const bf16* gB = B + (n0 + rowS) * K + c8;
    AS3 bf16* lA = (AS3 bf16*)sA + tid * 8;
    AS3 bf16* lB = (AS3 bf16*)sB + tid * 8;

    for (int k0 = 0; k0 < K; k0 += 32) {
        __syncthreads();
        __builtin_amdgcn_global_load_lds((const AS1 void*)(gA + k0),          (AS3 void*)lA,          16, 0, 0);
        __builtin_amdgcn_global_load_lds((const AS1 void*)(gA + 64 * K + k0), (AS3 void*)(lA + 2048), 16, 0, 0);
        __builtin_amdgcn_global_load_lds((const AS1 void*)(gB + k0),          (AS3 void*)lB,          16, 0, 0);
        __builtin_amdgcn_global_load_lds((const AS1 void*)(gB + 64 * K + k0), (AS3 void*)(lB + 2048), 16, 0, 0);
        __syncthreads();

        bf16x8 a[4], b[4];
#pragma unroll
        for (int t = 0; t < 4; t++)
            a[t] = *(const bf16x8*)(sA + (wr + t * 16 + l16) * 32 + quad * 8);
#pragma unroll
        for (int t = 0; t < 4; t++)
            b[t] = *(const bf16x8*)(sB + (wc + t * 16 + l16) * 32 + quad * 8);
#pragma unroll
        for (int i = 0; i < 4; i++)
#pragma unroll
            for (int j = 0; j < 4; j++)
                acc[i][j] = __builtin_amdgcn_mfma_f32_16x16x32_bf16(a[i], b[j], acc[i][j], 0, 0, 0);
    }

#pragma unroll
    for (int i = 0; i < 4; i++) {
        const int r0 = m0 + wr + i * 16 + quad * 4;
#pragma unroll
        for (int j = 0; j < 4; j++) {
            const int c = n0 + wc + j * 16 + l16;
#pragma unroll
            for (int r = 0; r < 4; r++)
                C[(size_t)(r0 + r) * N + c] = (CT)acc[i][j][r];
        }
    }
}

// ---------------------------------------------------------------------------
// RoPE in-place on Q and K.  One thread per (s, pair); each thread applies
// its rotation to 4 sites (b=0,1 x Q,K).
// pair pr = h*64 + p; cols 2pr, 2pr+1; phase = s * 10000^(-p/64).
// ---------------------------------------------------------------------------
__global__ __launch_bounds__(256) void rope_kernel(bf16* __restrict__ Q,
                                                   bf16* __restrict__ K)
{
    const int idx = blockIdx.x * 256 + threadIdx.x;   // 2048*1024 threads
    const int pr  = idx & 1023;
    const int s   = idx >> 10;
    const int p   = pr & 63;

    // log2(10000)/64 = 0.20762050593046836
    const float ph = (float)s * exp2f(-(float)p * 0.20762050593046836f);
    float sn, cs;
    sincosf(ph, &sn, &cs);

#pragma unroll
    for (int t = 0; t < 2; t++) {
        bf16* P = t ? K : Q;
#pragma unroll
        for (int b = 0; b < 2; b++) {
            bf16* ptr = P + (size_t)(b * SEQ + s) * DMODEL + pr * 2;
            bf16x2 v = *(const bf16x2*)ptr;
            const float x1 = (float)v[0], x2 = (float)v[1];
            bf16x2 r;
            r[0] = (bf16)(x1 * cs - x2 * sn);
            r[1] = (bf16)(x1 * sn + x2 * cs);
            *(bf16x2*)ptr = r;
        }
    }
}

// ---------------------------------------------------------------------------
// V transpose: V [b*S+s][h*128+d] -> Vt [(b*16+h)*128+d][s]
// ---------------------------------------------------------------------------
__global__ __launch_bounds__(256) void vtrans(const bf16* __restrict__ V,
                                              bf16* __restrict__ Vt)
{
    __shared__ bf16 t[32][33];
    const int bh = blockIdx.z;
    const int s0 = blockIdx.x * 32;
    const int d0 = blockIdx.y * 32;
    const int b = bh >> 4, h = bh & 15;
    const int tx = threadIdx.x & 31, ty = threadIdx.x >> 5;

#pragma unroll
    for (int i = 0; i < 4; i++) {
        const int s = s0 + ty + i * 8;
        t[ty + i * 8][tx] = V[(size_t)(b * SEQ + s) * DMODEL + h * DK + d0 + tx];
    }
    __syncthreads();
#pragma unroll
    for (int i = 0; i < 4; i++) {
        const int d = d0 + ty + i * 8;
        Vt[(size_t)(bh * DK + d) * SEQ + s0 + tx] = t[tx][ty + i * 8];
    }
}

// ---------------------------------------------------------------------------
// Flash-style causal MFMA attention v3.
// Block = 4 waves, BM=128 q-rows; each wave owns 32 q-rows (2 groups of 16).
// KVBLK=64.  Swapped QK^T: s = mfma(K-frag, Q-frag) ->
//   S[kv = kt*64 + sub*16 + quad*4 + r][q = qgroup + l16]  (lane l16 = q-row)
// so the softmax row-reduce is in-lane over 16 regs + shfl_xor(16|32).
// Each kb fragment read from LDS feeds BOTH q-groups' MFMAs; each vf
// fragment feeds both groups' PV MFMAs -> LDS read traffic per FLOP halved
// vs v2.  All LDS tiles XOR-swizzled (T2): byte ^= (row&7)<<4, applied on
// both write (reg-staged) and read sides -> 16-row b128 column reads are
// 2-way (free) instead of 4-bank-stride 8-way-ish.
// T14: next tile's K/V global->reg loads issued before compute.
// Balanced LPT: direction of qt sweep alternates with (y^z)&1 so
// co-resident block pairs sum to constant work.
// ---------------------------------------------------------------------------
#define NEG 3.0e4f

__device__ __forceinline__ bf16* swzK(bf16* base, int row, int bcol) {
    // 256 B rows (128 bf16 cols)
    return (bf16*)((char*)base + (((row << 8) + bcol) ^ ((row & 7) << 4)));
}
__device__ __forceinline__ const bf16* swzKc(const bf16* base, int row, int bcol) {
    return (const bf16*)((const char*)base + (((row << 8) + bcol) ^ ((row & 7) << 4)));
}
__device__ __forceinline__ bf16* swzV(bf16* base, int row, int bcol) {
    // 128 B rows (64 bf16 cols)
    return (bf16*)((char*)base + (((row << 7) + bcol) ^ ((row & 7) << 4)));
}
__device__ __forceinline__ const bf16* swzVc(const bf16* base, int row, int bcol) {
    return (const bf16*)((const char*)base + (((row << 7) + bcol) ^ ((row & 7) << 4)));
}

__global__ __launch_bounds__(256, 2) void attn(
    const bf16* __restrict__ Q, const bf16* __restrict__ K,
    const bf16* __restrict__ Vt, bf16* __restrict__ O)
{
    // balanced-pair LPT: alternate sweep direction by (y^z) parity
    const int rev = (blockIdx.y ^ blockIdx.z) & 1;
    const int qt = rev ? (gridDim.x - 1 - blockIdx.x) : blockIdx.x;
    const int h = blockIdx.y, b = blockIdx.z;
    const int tid = threadIdx.x, lane = tid & 63, wave = tid >> 6;
    const int l16 = lane & 15, quad = lane >> 4;

    __shared__ __align__(16) bf16 sK[64 * 128];     // 16 KB, swizzled
    __shared__ __align__(16) bf16 sV[128 * 64];     // 16 KB, swizzled
    __shared__ __align__(16) bf16 sP[4 * 32 * 64];  // 16 KB, swizzled

    const int q0 = qt * 128 + wave * 32;            // wave's first q-row
    bf16* sPw = sP + wave * 2048;                   // wave's 32x64 P tile

    // Q fragments for both 16-row groups: qf[g][dc]
    bf16x8 qf[2][4];
#pragma unroll
    for (int g = 0; g < 2; g++) {
        const bf16* gQ = Q + (size_t)(b * SEQ + q0 + g * 16 + l16) * DMODEL + h * DK + quad * 8;
#pragma unroll
        for (int dc = 0; dc < 4; dc++) qf[g][dc] = *(const bf16x8*)(gQ + dc * 32);
    }

    f32x4 o[2][8] = {};
    float mrow[2] = {-NEG, -NEG};   // per-lane stats for q = q0+16g+l16
    float lrow[2] = {0.f, 0.f};

    const bf16* gK = K + (size_t)(b * SEQ) * DMODEL + h * DK;
    const bf16* gV = Vt + (size_t)((b * NH + h) * DK) * SEQ;

    const float scale = 0.12751744154470187f;  // (1/sqrt(128)) * log2(e)
    const int nkt = 2 * qt + 2;                // 64-wide kv tiles

    // staging geometry: 4 x bf16x8 per thread per tensor
    const int rK = tid >> 4;           // K rows rK + 16*i   (0..63)
    const int cK = (tid & 15) * 8;     // K col chunk (elems)
    const int dV = tid >> 3;           // Vt rows dV + 32*i  (0..127)
    const int cV = (tid & 7) * 8;      // kv col chunk (elems)

    bf16x8 kreg[4], vreg[4];
    {   // prologue: load tile 0
#pragma unroll
        for (int i = 0; i < 4; i++)
            kreg[i] = *(const bf16x8*)(gK + (size_t)(rK + 16 * i) * DMODEL + cK);
#pragma unroll
        for (int i = 0; i < 4; i++)
            vreg[i] = *(const bf16x8*)(gV + (size_t)(dV + 32 * i) * SEQ + cV);
    }

    for (int kt = 0; kt < nkt; kt++) {
        __syncthreads();               // prev compute done with LDS
#pragma unroll
        for (int i = 0; i < 4; i++)
            *(bf16x8*)swzK(sK, rK + 16 * i, cK * 2) = kreg[i];
#pragma unroll
        for (int i = 0; i < 4; i++)
            *(bf16x8*)swzV(sV, dV + 32 * i, cV * 2) = vreg[i];
        __syncthreads();

        if (kt + 1 < nkt) {            // T14: issue next tile early
            const int kb0 = (kt + 1) * 64;
#pragma unroll
            for (int i = 0; i < 4; i++)
                kreg[i] = *(const bf16x8*)(gK + (size_t)(kb0 + rK + 16 * i) * DMODEL + cK);
#pragma unroll
            for (int i = 0; i < 4; i++)
                vreg[i] = *(const bf16x8*)(gV + (size_t)(dV + 32 * i) * SEQ + kb0 + cV);
        }

        // wave-uniform causal skip (q0 multiple of 32, kt*64 multiple of 32:
        // groups 0 and 1 are active under exactly the same condition)
        if (kt * 64 <= q0 + 15) {
            // ---- QK^T, swapped operands; kb shared by both q-groups ----
            f32x4 s4[2][4] = {};
            __builtin_amdgcn_s_setprio(1);
#pragma unroll
            for (int sub = 0; sub < 4; sub++)
#pragma unroll
                for (int dc = 0; dc < 4; dc++) {
                    bf16x8 kb = *(const bf16x8*)swzKc(sK, sub * 16 + l16, dc * 64 + quad * 16);
                    s4[0][sub] = __builtin_amdgcn_mfma_f32_16x16x32_bf16(kb, qf[0][dc], s4[0][sub], 0, 0, 0);
                    s4[1][sub] = __builtin_amdgcn_mfma_f32_16x16x32_bf16(kb, qf[1][dc], s4[1][sub], 0, 0, 0);
                }
            __builtin_amdgcn_s_setprio(0);

            // ---- mask + in-lane softmax, per group ----
#pragma unroll
            for (int g = 0; g < 2; g++) {
                const int qg = q0 + g * 16 + l16;
                const int kb0 = kt * 64 + quad * 4;
                float arr[16];
                float mx = -NEG;
#pragma unroll
                for (int sub = 0; sub < 4; sub++)
#pragma unroll
                    for (int r = 0; r < 4; r++) {
                        const int key = kb0 + sub * 16 + r;
                        const float val = (key <= qg) ? s4[g][sub][r] * scale : -NEG;
                        arr[sub * 4 + r] = val;
                        mx = fmaxf(mx, val);
                    }
                mx = fmaxf(mx, __shfl_xor(mx, 16));
                mx = fmaxf(mx, __shfl_xor(mx, 32));
                const float mnew  = fmaxf(mrow[g], mx);
                const float alpha = exp2f(mrow[g] - mnew);
                mrow[g] = mnew;
                float ps = 0.f;
#pragma unroll
                for (int i = 0; i < 16; i++) {
                    arr[i] = exp2f(arr[i] - mnew);
                    ps += arr[i];
                }
                ps += __shfl_xor(ps, 16);
                ps += __shfl_xor(ps, 32);
                lrow[g] = lrow[g] * alpha + ps;

                // P -> sP (row q=16g+l16, col kv), swizzled
#pragma unroll
                for (int sub = 0; sub < 4; sub++) {
                    bf16x4 pk;
                    pk[0] = (bf16)arr[sub * 4 + 0];
                    pk[1] = (bf16)arr[sub * 4 + 1];
                    pk[2] = (bf16)arr[sub * 4 + 2];
                    pk[3] = (bf16)arr[sub * 4 + 3];
                    *(bf16x4*)swzV(sPw, g * 16 + l16, sub * 32 + quad * 8) = pk;
                }

                // rescale o: alpha for o-row (quad*4+r) via width-16 shfl
#pragma unroll
                for (int r = 0; r < 4; r++) {
                    const float ar = __shfl(alpha, quad * 4 + r, 16);
#pragma unroll
                    for (int dt = 0; dt < 8; dt++) o[g][dt][r] *= ar;
                }
            }

            asm volatile("s_waitcnt lgkmcnt(0)" ::: "memory");
            __builtin_amdgcn_sched_barrier(0);

            // ---- PV: A-frag A[m=q(l16)][k=kv(quad*8+j)]; vf shared ----
            bf16x8 pf0[2], pf1[2];
#pragma unroll
            for (int g = 0; g < 2; g++) {
                pf0[g] = *(const bf16x8*)swzVc(sPw, g * 16 + l16, quad * 16);
                pf1[g] = *(const bf16x8*)swzVc(sPw, g * 16 + l16, 64 + quad * 16);
            }
            __builtin_amdgcn_s_setprio(1);
#pragma unroll
            for (int dt = 0; dt < 8; dt++) {
                bf16x8 vf0 = *(const bf16x8*)swzVc(sV, dt * 16 + l16, quad * 16);
                bf16x8 vf1 = *(const bf16x8*)swzVc(sV, dt * 16 + l16, 64 + quad * 16);
                o[0][dt] = __builtin_amdgcn_mfma_f32_16x16x32_bf16(pf0[0], vf0, o[0][dt], 0, 0, 0);
                o[0][dt] = __builtin_amdgcn_mfma_f32_16x16x32_bf16(pf1[0], vf1, o[0][dt], 0, 0, 0);
                o[1][dt] = __builtin_amdgcn_mfma_f32_16x16x32_bf16(pf0[1], vf0, o[1][dt], 0, 0, 0);
                o[1][dt] = __builtin_amdgcn_mfma_f32_16x16x32_bf16(pf1[1], vf1, o[1][dt], 0, 0, 0);
            }
            __builtin_amdgcn_s_setprio(0);
        }
    }

    // epilogue: l for o-row (quad*4+r) via width-16 shfl, then divide+store
#pragma unroll
    for (int g = 0; g < 2; g++) {
        bf16* gO = O + (size_t)(b * SEQ + q0 + g * 16 + quad * 4) * DMODEL + h * DK + l16;
#pragma unroll
        for (int r = 0; r < 4; r++) {
            const float lr = __shfl(lrow[g], quad * 4 + r, 16);
            const float inv = 1.0f / lr;
#pragma unroll
            for (int dt = 0; dt < 8; dt++)
                gO[(size_t)r * DMODEL + dt * 16] = (bf16)(o[g][dt][r] * inv);
        }
    }
}

// ---------------------------------------------------------------------------
extern "C" void kernel_launch(void* const* d_in, const int* in_sizes, int n_in,
                              void* d_out, int out_size, void* d_ws, size_t ws_size,
                              hipStream_t stream)
{
    const float* x  = (const float*)d_in[0];
    const float* Wq = (const float*)d_in[2];
    const float* Wk = (const float*)d_in[3];
    const float* Wv = (const float*)d_in[4];
    const float* Wo = (const float*)d_in[5];

    const int M = 2 * SEQ;       // 4096
    const int N = DMODEL;        // 2048
    const int Kd = DMODEL;       // 2048
    const size_t tsz = (size_t)M * N;   // 8.4M elems
    const size_t wsz = (size_t)N * Kd;  // 4.2M elems

    // Workspace layout (bf16): xb | Wqb Wkb Wvb Wob | Qb Kb Vb  = 100.7 MB
    bf16* xb  = (bf16*)d_ws;
    bf16* Wqb = xb  + tsz;
    bf16* Wkb = Wqb + wsz;
    bf16* Wvb = Wkb + wsz;
    bf16* Wob = Wvb + wsz;
    bf16* Qb  = Wob + wsz;
    bf16* Kb  = Qb  + tsz;
    bf16* Vb  = Kb  + tsz;
    bf16* Vt  = (bf16*)d_out;    // scratch in d_out (33.5 MB as f32); fully
                                 // overwritten by the final f32 GEMM stores
    bf16* Ab  = Vb;              // alias: Vb dead once Vt is built

    // 0) cast all f32 inputs to bf16
    cast_f32_bf16<<<dim3(tsz / 1024, 1, 5), 256, 0, stream>>>(
        x, Wq, Wk, Wv, Wo, xb, Wqb, Wkb, Wvb, Wob);

    // 1) Q,K,V projections (fused via grid.z), bf16 outputs
    gemm_bt<bf16><<<dim3(N / 128, M / 128, 3), 256, 0, stream>>>(
        xb, Wqb, Wkb, Wvb, Qb, Kb, Vb, M, N, Kd);

    // 2) RoPE on Q and K (1 sincos per (s,pair) -> 4 sites)
    rope_kernel<<<(SEQ * 1024) / 256, 256, 0, stream>>>(Qb, Kb);

    // 3) transpose V per (b,h) into d_out scratch
    vtrans<<<dim3(SEQ / 32, DK / 32, 2 * NH), 256, 0, stream>>>(Vb, Vt);

    // 4) causal flash attention -> Ab (Vb's storage)
    attn<<<dim3(SEQ / 128, NH, 2), 256, 0, stream>>>(Qb, Kb, Vt, Ab);

    // 5) output projection -> d_out, FLOAT32 stores (reference output dtype)
    gemm_bt<float><<<dim3(N / 128, M / 128, 1), 256, 0, stream>>>(
        Ab, Wob, Wob, Wob, (float*)d_out, (float*)d_out, (float*)d_out, M, N, Kd);
}